// Round 7
// baseline (1047.121 us; speedup 1.0000x reference)
//
#include <hip/hip_runtime.h>
#include <hip/hip_bf16.h>

#define N_NODES 50000
#define N_EDGES 800000
#define DIM 128
#define HID 256
#define N_GRAPH 512
#define N_LAYER 3
#define EFEAT 8
#define BN_EPS 1e-5f

typedef unsigned short u16;
typedef unsigned int u32;

using bf16x8_t = short __attribute__((ext_vector_type(8)));
using f32x4_t  = float __attribute__((ext_vector_type(4)));
using f32x2    = float __attribute__((ext_vector_type(2)));

// ---------------------------------------------------------------- utilities
__device__ __forceinline__ void atomic_add_f(float* p, float v) { unsafeAtomicAdd(p, v); }
__device__ __forceinline__ u16 f2bf(float x) {
    union { float f; u32 u; } v; v.f = x;
    u32 r = v.u + 0x7FFF + ((v.u >> 16) & 1);
    return (u16)(r >> 16);
}
__device__ __forceinline__ float bf2f(u16 u) {
    union { u32 i; float f; } v; v.i = (u32)u << 16; return v.f;
}
__device__ __forceinline__ float2 up2(u32 p) {
    return make_float2(bf2f((u16)(p & 0xFFFF)), bf2f((u16)(p >> 16)));
}
__device__ __forceinline__ u32 pk2(float a, float b) {
    return (u32)f2bf(a) | ((u32)f2bf(b) << 16);
}
__device__ __forceinline__ u32 ld32(const u16* base, u32 boff) {
    return *(const u32*)((const char*)base + boff);
}

// ---------------------------------------------------------------- weight transpose+convert to bf16
__global__ __launch_bounds__(256) void wconv_kernel(
    const float* __restrict__ W1, const float* __restrict__ W2,
    u16* __restrict__ W1t, u16* __restrict__ W2t)
{
    int idx = blockIdx.x * 256 + threadIdx.x;
    if (idx >= 6 * 32768) return;
    int m = idx >> 15;
    int off = idx & 32767;
    int l = m >> 1;
    if ((m & 1) == 0) {
        int r = off >> 8, c = off & 255;
        W1t[(size_t)l * 32768 + c * 128 + r] = f2bf(W1[(size_t)l * 32768 + r * 256 + c]);
    } else {
        int r = off >> 7, c = off & 127;
        W2t[(size_t)l * 32768 + c * 256 + r] = f2bf(W2[(size_t)l * 32768 + r * 128 + c]);
    }
}

// ---------------------------------------------------------------- CSR build
__global__ __launch_bounds__(256) void hist_kernel(const int* __restrict__ ei, int* __restrict__ deg) {
    int e = blockIdx.x * 256 + threadIdx.x;
    if (e < N_EDGES) atomicAdd(&deg[ei[N_EDGES + e]], 1);
}

// exclusive scan deg -> rowptr, then zero deg (reused as cursor by scatter)
__global__ __launch_bounds__(1024) void scan_kernel(int* __restrict__ deg, int* __restrict__ rowptr) {
    __shared__ int wsum[16];
    __shared__ int carry;
    int tid = threadIdx.x;
    if (tid == 0) { carry = 0; rowptr[0] = 0; }
    __syncthreads();
    for (int base = 0; base < N_NODES; base += 1024) {
        int i = base + tid;
        int v = (i < N_NODES) ? deg[i] : 0;
        int lane = tid & 63, w = tid >> 6;
        int s = v;
        #pragma unroll
        for (int d = 1; d < 64; d <<= 1) { int t = __shfl_up(s, d); if (lane >= d) s += t; }
        if (lane == 63) wsum[w] = s;
        __syncthreads();
        if (tid < 64) {
            int t = (tid < 16) ? wsum[tid] : 0;
            #pragma unroll
            for (int d = 1; d < 16; d <<= 1) { int u = __shfl_up(t, d); if (tid >= d) t += u; }
            if (tid < 16) wsum[tid] = t;
        }
        __syncthreads();
        int excl = (w > 0) ? wsum[w - 1] : 0;
        int incl = s + excl + carry;
        if (i < N_NODES) rowptr[i + 1] = incl;
        __syncthreads();
        if (tid == 0) carry += wsum[15];
        __syncthreads();
    }
    for (int i = tid; i < N_NODES; i += 1024) deg[i] = 0;
}

// sE holds BYTE offsets: (src*DIM*2, e*EFEAT*4)
__global__ __launch_bounds__(256) void scatter_kernel(
    const int* __restrict__ ei, const int* __restrict__ rowptr,
    int* __restrict__ cursor, int2* __restrict__ sE)
{
    int e = blockIdx.x * 256 + threadIdx.x;
    if (e >= N_EDGES) return;
    int dst = ei[N_EDGES + e];
    int p = atomicAdd(&cursor[dst], 1);
    sE[rowptr[dst] + p] = make_int2(ei[e] * (DIM * 2), e * (EFEAT * 4));
}

// ---------------------------------------------------------------- h_in = act(src) + vn[batch]  (bf16 out)
template <bool USEBN, int VNM>
__global__ __launch_bounds__(256) void hin_kernel(
    const float* __restrict__ src,
    const float* __restrict__ sum2, const float* __restrict__ ss2,
    const float* __restrict__ g, const float* __restrict__ b, float invN,
    const int* __restrict__ batch,
    const float* __restrict__ vn_emb,
    const float* __restrict__ vnpre, const float* __restrict__ vsum, const float* __restrict__ vss,
    const float* __restrict__ gv, const float* __restrict__ btv, float invG,
    u16* __restrict__ hin, int total4)
{
    int idx = blockIdx.x * 256 + threadIdx.x;
    if (idx >= total4) return;
    int base = idx * 4;
    int n = base >> 7;
    int c = base & (DIM - 1);
    float4 v = *(const float4*)(src + base);
    float o[4] = {v.x, v.y, v.z, v.w};
    if (USEBN) {
        #pragma unroll
        for (int j = 0; j < 4; ++j) {
            int cj = c + j;
            float m = sum2[cj] * invN;
            float var = ss2[cj] * invN - m * m;
            float r = rsqrtf(var + BN_EPS);
            float a = g[cj] * r;
            o[j] = fmaxf(fmaf(a, o[j], b[cj] - m * a), 0.f);
        }
    }
    int grp = batch[n];
    if (VNM == 0) {
        const float4 w = *(const float4*)(vn_emb + c);
        o[0] += w.x; o[1] += w.y; o[2] += w.z; o[3] += w.w;
    } else {
        const float4 vp = *(const float4*)(vnpre + (size_t)grp * DIM + c);
        float vv[4] = {vp.x, vp.y, vp.z, vp.w};
        #pragma unroll
        for (int j = 0; j < 4; ++j) {
            int cj = c + j;
            float m = vsum[cj] * invG;
            float var = vss[cj] * invG - m * m;
            float r = rsqrtf(var + BN_EPS);
            float a = gv[cj] * r;
            o[j] += fmaxf(fmaf(a, vv[j], btv[cj] - m * a), 0.f);
        }
    }
    uint2 pk;
    pk.x = pk2(o[0], o[1]);
    pk.y = pk2(o[2], o[3]);
    *(uint2*)(hin + base) = pk;
}

// ---------------------------------------------------------------- gather aggregation (f32x2 packed math)
__device__ __forceinline__ void edge_term_f(
    u32 h, float4 alo, float4 ahi, const f32x2* rW, f32x2 rB, f32x2& acc)
{
    f32x2 e = rB;
    e += alo.x * rW[0]; e += alo.y * rW[1];
    e += alo.z * rW[2]; e += alo.w * rW[3];
    e += ahi.x * rW[4]; e += ahi.y * rW[5];
    e += ahi.z * rW[6]; e += ahi.w * rW[7];
    f32x2 hv;
    hv.x = bf2f((u16)(h & 0xFFFF));
    hv.y = bf2f((u16)(h >> 16));
    f32x2 m = hv + e;
    m.x = fmaxf(m.x, 0.f);
    m.y = fmaxf(m.y, 0.f);
    acc += m;
}

__global__ __launch_bounds__(256) void aggr_kernel(
    const int* __restrict__ rowptr, const int2* __restrict__ sE,
    const float* __restrict__ ea,
    const float* __restrict__ Wel, const float* __restrict__ bel,
    const u16* __restrict__ hin, u16* __restrict__ z,
    float* __restrict__ statsZ)
{
    if (blockIdx.x == 0) {      // zero this layer's stats buffer (consumed only after aggr)
        for (int i = threadIdx.x; i < 2048; i += 256) statsZ[i] = 0.f;
    }
    int node = blockIdx.x * 4 + (threadIdx.x >> 6);
    if (node >= N_NODES) return;
    int lane = threadIdx.x & 63;
    int c = lane * 2;
    const u32 cb = (u32)lane * 4u;

    f32x2 rW[EFEAT];
    #pragma unroll
    for (int k = 0; k < EFEAT; ++k) {
        float2 t = *(const float2*)(Wel + k * DIM + c);
        rW[k].x = t.x; rW[k].y = t.y;
    }
    f32x2 rB;
    { float2 t = *(const float2*)(bel + c); rB.x = t.x; rB.y = t.y; }

    const u32 ownb = (u32)node * (DIM * 2) + cb;
    float2 own = up2(ld32(hin, ownb));
    f32x2 acc; acc.x = own.x; acc.y = own.y;
    int beg = rowptr[node], end = rowptr[node + 1];

    const char* eab = (const char*)ea;
    int i = beg;
    if ((i & 1) && i < end) {
        int2 s0 = sE[i];
        u32 h0 = ld32(hin, (u32)s0.x + cb);
        float4 a0l = *(const float4*)(eab + (u32)s0.y);
        float4 a0h = *(const float4*)(eab + (u32)s0.y + 16);
        edge_term_f(h0, a0l, a0h, rW, rB, acc);
        ++i;
    }
    for (; i + 3 < end; i += 4) {
        int4 sp0 = *(const int4*)(sE + i);
        int4 sp1 = *(const int4*)(sE + i + 2);
        u32 h0 = ld32(hin, (u32)sp0.x + cb);
        u32 h1 = ld32(hin, (u32)sp0.z + cb);
        u32 h2 = ld32(hin, (u32)sp1.x + cb);
        u32 h3 = ld32(hin, (u32)sp1.z + cb);
        float4 a0l = *(const float4*)(eab + (u32)sp0.y);
        float4 a0h = *(const float4*)(eab + (u32)sp0.y + 16);
        float4 a1l = *(const float4*)(eab + (u32)sp0.w);
        float4 a1h = *(const float4*)(eab + (u32)sp0.w + 16);
        float4 a2l = *(const float4*)(eab + (u32)sp1.y);
        float4 a2h = *(const float4*)(eab + (u32)sp1.y + 16);
        float4 a3l = *(const float4*)(eab + (u32)sp1.w);
        float4 a3h = *(const float4*)(eab + (u32)sp1.w + 16);
        edge_term_f(h0, a0l, a0h, rW, rB, acc);
        edge_term_f(h1, a1l, a1h, rW, rB, acc);
        edge_term_f(h2, a2l, a2h, rW, rB, acc);
        edge_term_f(h3, a3l, a3h, rW, rB, acc);
    }
    for (; i < end; ++i) {
        int2 s0 = sE[i];
        u32 h0 = ld32(hin, (u32)s0.x + cb);
        float4 a0l = *(const float4*)(eab + (u32)s0.y);
        float4 a0h = *(const float4*)(eab + (u32)s0.y + 16);
        edge_term_f(h0, a0l, a0h, rW, rB, acc);
    }
    *(u32*)((char*)z + ownb) = pk2(acc.x, acc.y);
}

// ---------------------------------------------------------------- LDS-free bf16 MFMA GEMM
// Block = 256 threads = 2x2 waves. Wave tile = 64 rows x (NI*16) cols. Block tile = 128 x NI*32.
// Fragments loaded DIRECTLY from global (A: L1/L2, B: L2-resident weights). No staging, no
// mid-loop barriers — waves fully independent; latency hidden by MLP. 2 barriers total (stats).
// Epilogue: bias add, C store, per-column sum/sumsq -> global atomics.
template <int KK, int NI, bool CBF16>
__global__ __launch_bounds__(256) void gemm_mfma_kernel(
    const u16* __restrict__ Aa,          // [M][KK] bf16
    const u16* __restrict__ Bt,          // [Nc][KK] bf16 (pre-transposed)
    const float* __restrict__ bias,
    void* __restrict__ CoutV,
    float* __restrict__ outSum, float* __restrict__ outSS,
    int M, int Nc)
{
    constexpr int BN = NI * 32;
    __shared__ float csum[BN], css[BN];

    const int tid = threadIdx.x;
    const int wave = tid >> 6, lane = tid & 63;
    const int row0 = blockIdx.x * 128, col0 = blockIdx.y * BN;
    const int w_m = (wave & 1) * 64;
    const int w_n = (wave >> 1) * (NI * 16);
    const int quad = lane >> 4, l16 = lane & 15;

    if (tid < BN) { csum[tid] = 0.f; css[tid] = 0.f; }
    __syncthreads();

    f32x4_t acc[4][NI];
    #pragma unroll
    for (int mi = 0; mi < 4; ++mi)
        #pragma unroll
        for (int ni = 0; ni < NI; ++ni)
            acc[mi][ni] = (f32x4_t){0.f, 0.f, 0.f, 0.f};

    const u16* aptr[4];
    #pragma unroll
    for (int mi = 0; mi < 4; ++mi) {
        int gr = row0 + w_m + mi * 16 + l16;
        if (gr >= M) gr = M - 1;
        aptr[mi] = Aa + (size_t)gr * KK + quad * 8;
    }
    const u16* bptr[NI];
    #pragma unroll
    for (int ni = 0; ni < NI; ++ni)
        bptr[ni] = Bt + (size_t)(col0 + w_n + ni * 16 + l16) * KK + quad * 8;

    constexpr int NKS = KK / 32;
    #pragma unroll
    for (int ks = 0; ks < NKS; ++ks) {
        bf16x8_t a[4], b[NI];
        #pragma unroll
        for (int mi = 0; mi < 4; ++mi)
            a[mi] = *(const bf16x8_t*)(aptr[mi] + ks * 32);
        #pragma unroll
        for (int ni = 0; ni < NI; ++ni)
            b[ni] = *(const bf16x8_t*)(bptr[ni] + ks * 32);
        #pragma unroll
        for (int mi = 0; mi < 4; ++mi)
            #pragma unroll
            for (int ni = 0; ni < NI; ++ni)
                acc[mi][ni] = __builtin_amdgcn_mfma_f32_16x16x32_bf16(
                    a[mi], b[ni], acc[mi][ni], 0, 0, 0);
    }

    // epilogue: C layout col=lane&15, row=quad*4+reg
    u16* Cb = (u16*)CoutV;
    float* Cf = (float*)CoutV;
    #pragma unroll
    for (int ni = 0; ni < NI; ++ni) {
        int ccol = w_n + ni * 16 + l16;
        int col = col0 + ccol;
        float bv = bias[col];
        float s = 0.f, qs = 0.f;
        #pragma unroll
        for (int mi = 0; mi < 4; ++mi) {
            int rbase = row0 + w_m + mi * 16 + quad * 4;
            #pragma unroll
            for (int reg = 0; reg < 4; ++reg) {
                int gr = rbase + reg;
                if (gr < M) {
                    float o = acc[mi][ni][reg] + bv;
                    s += o;
                    qs += o * o;
                    if (CBF16) Cb[(size_t)gr * Nc + col] = f2bf(o);
                    else       Cf[(size_t)gr * Nc + col] = o;
                }
            }
        }
        s += __shfl_xor(s, 16);  s += __shfl_xor(s, 32);
        qs += __shfl_xor(qs, 16);  qs += __shfl_xor(qs, 32);
        if (quad == 0) {
            atomicAdd(&csum[ccol], s);
            atomicAdd(&css[ccol], qs);
        }
    }
    __syncthreads();
    if (tid < BN) {
        atomic_add_f(outSum + col0 + tid, csum[tid]);
        atomic_add_f(outSS + col0 + tid, css[tid]);
    }
}

// ---------------------------------------------------------------- in-place BN+ReLU on bf16 [rows x HID]
__global__ __launch_bounds__(256) void bnrelu_kernel(
    u16* __restrict__ buf,
    const float* __restrict__ sSum, const float* __restrict__ sSS,
    const float* __restrict__ g, const float* __restrict__ bt, float invCnt, int total8)
{
    int idx = blockIdx.x * 256 + threadIdx.x;
    if (idx >= total8) return;
    int base = idx * 8;
    int cj = base & (HID - 1);
    uint4 q = *(uint4*)(buf + base);
    const float4 s0 = *(const float4*)(sSum + cj);
    const float4 s1 = *(const float4*)(sSum + cj + 4);
    const float4 q0 = *(const float4*)(sSS + cj);
    const float4 q1 = *(const float4*)(sSS + cj + 4);
    const float4 g0 = *(const float4*)(g + cj);
    const float4 g1 = *(const float4*)(g + cj + 4);
    const float4 t0 = *(const float4*)(bt + cj);
    const float4 t1 = *(const float4*)(bt + cj + 4);
    float sm[8] = {s0.x, s0.y, s0.z, s0.w, s1.x, s1.y, s1.z, s1.w};
    float sq[8] = {q0.x, q0.y, q0.z, q0.w, q1.x, q1.y, q1.z, q1.w};
    float gg[8] = {g0.x, g0.y, g0.z, g0.w, g1.x, g1.y, g1.z, g1.w};
    float tt[8] = {t0.x, t0.y, t0.z, t0.w, t1.x, t1.y, t1.z, t1.w};
    u32 w[4] = {q.x, q.y, q.z, q.w};
    #pragma unroll
    for (int p = 0; p < 4; ++p) {
        float2 v = up2(w[p]);
        float m0 = sm[p * 2] * invCnt;
        float var0 = sq[p * 2] * invCnt - m0 * m0;
        float a0 = gg[p * 2] * rsqrtf(var0 + BN_EPS);
        float m1 = sm[p * 2 + 1] * invCnt;
        float var1 = sq[p * 2 + 1] * invCnt - m1 * m1;
        float a1 = gg[p * 2 + 1] * rsqrtf(var1 + BN_EPS);
        v.x = fmaxf(fmaf(a0, v.x, tt[p * 2] - m0 * a0), 0.f);
        v.y = fmaxf(fmaf(a1, v.y, tt[p * 2 + 1] - m1 * a1), 0.f);
        w[p] = pk2(v.x, v.y);
    }
    q.x = w[0]; q.y = w[1]; q.z = w[2]; q.w = w[3];
    *(uint4*)(buf + base) = q;
}

// ---------------------------------------------------------------- fp32 GEMM (VN path)
// MODE 1: A = relu(alpha*Aa+beta)
// MODE 2: A = Aa + vadd[k]
// MODE 3: A = Aa + relu(alpha*Ab[gr,k]+beta)
// ZP: zero zbuf (pooled re-init for next layer)
template <int MODE, bool ZP>
__global__ __launch_bounds__(256) void gemm_kernel(
    const float* __restrict__ Aa, const float* __restrict__ Ab, const float* __restrict__ vadd,
    const float* __restrict__ sSum, const float* __restrict__ sSS,
    const float* __restrict__ gA, const float* __restrict__ btA, float invCnt,
    const float* __restrict__ B, const float* __restrict__ bias,
    float* __restrict__ Cout, float* __restrict__ outSum, float* __restrict__ outSS,
    int M, int K, int Nc, float* __restrict__ zbuf)
{
    __shared__ float As[16][68];
    __shared__ float Bs[16][64];
    __shared__ float alphaS[256], betaS[256];
    __shared__ float csum[64], css[64];

    const int tid = threadIdx.x;
    const int tx = tid & 15, ty = tid >> 4;
    const int row0 = blockIdx.x * 64, col0 = blockIdx.y * 64;

    if (tid < 64) { csum[tid] = 0.f; css[tid] = 0.f; }
    if (MODE == 1 || MODE == 3) {
        for (int k = tid; k < K; k += 256) {
            float m = sSum[k] * invCnt;
            float var = sSS[k] * invCnt - m * m;
            float r = rsqrtf(var + BN_EPS);
            float a = gA[k] * r;
            alphaS[k] = a;
            betaS[k] = btA[k] - m * a;
        }
    } else if (MODE == 2) {
        for (int k = tid; k < K; k += 256) betaS[k] = vadd[k];
    }
    __syncthreads();

    float acc[4][4];
    #pragma unroll
    for (int i = 0; i < 4; ++i)
        #pragma unroll
        for (int j = 0; j < 4; ++j) acc[i][j] = 0.f;

    const int lr = tid >> 2;
    const int lk = (tid & 3) * 4;
    const int bk = tid >> 4;
    const int bc = tx * 4;

    for (int kt = 0; kt < K; kt += 16) {
        int gr = row0 + lr;
        float4 va = make_float4(0.f, 0.f, 0.f, 0.f);
        if (gr < M) {
            va = *(const float4*)(Aa + (size_t)gr * K + kt + lk);
            int k0 = kt + lk;
            if (MODE == 1) {
                va.x = fmaxf(fmaf(alphaS[k0 + 0], va.x, betaS[k0 + 0]), 0.f);
                va.y = fmaxf(fmaf(alphaS[k0 + 1], va.y, betaS[k0 + 1]), 0.f);
                va.z = fmaxf(fmaf(alphaS[k0 + 2], va.z, betaS[k0 + 2]), 0.f);
                va.w = fmaxf(fmaf(alphaS[k0 + 3], va.w, betaS[k0 + 3]), 0.f);
            } else if (MODE == 2) {
                va.x += betaS[k0 + 0]; va.y += betaS[k0 + 1];
                va.z += betaS[k0 + 2]; va.w += betaS[k0 + 3];
            } else if (MODE == 3) {
                const float4 vb = *(const float4*)(Ab + (size_t)gr * K + kt + lk);
                va.x += fmaxf(fmaf(alphaS[k0 + 0], vb.x, betaS[k0 + 0]), 0.f);
                va.y += fmaxf(fmaf(alphaS[k0 + 1], vb.y, betaS[k0 + 1]), 0.f);
                va.z += fmaxf(fmaf(alphaS[k0 + 2], vb.z, betaS[k0 + 2]), 0.f);
                va.w += fmaxf(fmaf(alphaS[k0 + 3], vb.w, betaS[k0 + 3]), 0.f);
            }
        }
        As[lk + 0][lr] = va.x;
        As[lk + 1][lr] = va.y;
        As[lk + 2][lr] = va.z;
        As[lk + 3][lr] = va.w;
        const float4 vb4 = *(const float4*)(B + (size_t)(kt + bk) * Nc + col0 + bc);
        *(float4*)&Bs[bk][bc] = vb4;
        __syncthreads();
        #pragma unroll
        for (int kk = 0; kk < 16; ++kk) {
            const float4 a4 = *(const float4*)&As[kk][ty * 4];
            const float4 b4 = *(const float4*)&Bs[kk][tx * 4];
            float av[4] = {a4.x, a4.y, a4.z, a4.w};
            float bv4[4] = {b4.x, b4.y, b4.z, b4.w};
            #pragma unroll
            for (int i = 0; i < 4; ++i)
                #pragma unroll
                for (int j = 0; j < 4; ++j)
                    acc[i][j] = fmaf(av[i], bv4[j], acc[i][j]);
        }
        __syncthreads();
    }

    const float4 bvv = *(const float4*)(bias + col0 + tx * 4);
    float bias4[4] = {bvv.x, bvv.y, bvv.z, bvv.w};
    float ps[4] = {0.f, 0.f, 0.f, 0.f};
    float pq[4] = {0.f, 0.f, 0.f, 0.f};
    #pragma unroll
    for (int i = 0; i < 4; ++i) {
        int gr = row0 + ty * 4 + i;
        if (gr < M) {
            float o[4];
            #pragma unroll
            for (int j = 0; j < 4; ++j) {
                o[j] = acc[i][j] + bias4[j];
                ps[j] += o[j];
                pq[j] += o[j] * o[j];
            }
            *(float4*)(Cout + (size_t)gr * Nc + col0 + tx * 4) = make_float4(o[0], o[1], o[2], o[3]);
        }
    }
    #pragma unroll
    for (int j = 0; j < 4; ++j) {
        atomicAdd(&csum[tx * 4 + j], ps[j]);
        atomicAdd(&css[tx * 4 + j], pq[j]);
    }
    __syncthreads();
    if (tid < 64) {
        atomic_add_f(outSum + col0 + tid, csum[tid]);
        atomic_add_f(outSS + col0 + tid, css[tid]);
    }
    if (ZP) {
        int flat = blockIdx.y * gridDim.x + blockIdx.x;
        float4* zp = (float4*)(zbuf + (size_t)flat * 4096 + tid * 16);
        zp[0] = make_float4(0.f, 0.f, 0.f, 0.f);
        zp[1] = make_float4(0.f, 0.f, 0.f, 0.f);
        zp[2] = make_float4(0.f, 0.f, 0.f, 0.f);
        zp[3] = make_float4(0.f, 0.f, 0.f, 0.f);
    }
}

// ---------------------------------------------------------------- pooled: chunked segment sum (batch sorted)
#define PCHUNK 256
__global__ __launch_bounds__(128) void pooled_chunk_kernel(
    const u16* __restrict__ hin, const int* __restrict__ batch, float* __restrict__ pooled)
{
    __shared__ int sb[PCHUNK];
    int n0 = blockIdx.x * PCHUNK;
    int cnt = N_NODES - n0; if (cnt > PCHUNK) cnt = PCHUNK;
    for (int i = threadIdx.x; i < cnt; i += 128) sb[i] = batch[n0 + i];
    __syncthreads();
    int c = threadIdx.x;
    int curg = sb[0];
    float acc = 0.f;
    for (int i = 0; i < cnt; ++i) {
        int g = sb[i];
        if (g != curg) {
            atomic_add_f(&pooled[(size_t)curg * DIM + c], acc);
            acc = 0.f;
            curg = g;
        }
        acc += bf2f(hin[(size_t)(n0 + i) * DIM + c]);
    }
    atomic_add_f(&pooled[(size_t)curg * DIM + c], acc);
}

// ---------------------------------------------------------------- final in-place BN on d_out (no relu)
__global__ __launch_bounds__(256) void final_bn_kernel(
    float* __restrict__ outp, const float* __restrict__ sum2, const float* __restrict__ ss2,
    const float* __restrict__ g, const float* __restrict__ b, float invN, int total4)
{
    int idx = blockIdx.x * 256 + threadIdx.x;
    if (idx >= total4) return;
    int base = idx * 4;
    int c = base & (DIM - 1);
    float4 v = *(const float4*)(outp + base);
    float o[4] = {v.x, v.y, v.z, v.w};
    #pragma unroll
    for (int j = 0; j < 4; ++j) {
        int cj = c + j;
        float m = sum2[cj] * invN;
        float var = ss2[cj] * invN - m * m;
        float r = rsqrtf(var + BN_EPS);
        float a = g[cj] * r;
        o[j] = fmaf(a, o[j], b[cj] - m * a);
    }
    *(float4*)(outp + base) = make_float4(o[0], o[1], o[2], o[3]);
}

// ---------------------------------------------------------------- launch
extern "C" void kernel_launch(void* const* d_in, const int* in_sizes, int n_in,
                              void* d_out, int out_size, void* d_ws, size_t ws_size,
                              hipStream_t stream) {
    const float* x         = (const float*)d_in[0];
    const float* edge_attr = (const float*)d_in[1];
    const float* vn_emb    = (const float*)d_in[2];
    const float* We        = (const float*)d_in[3];
    const float* be        = (const float*)d_in[4];
    const float* W1        = (const float*)d_in[5];
    const float* b1        = (const float*)d_in[6];
    const float* g1v       = (const float*)d_in[7];
    const float* bt1       = (const float*)d_in[8];
    const float* W2        = (const float*)d_in[9];
    const float* b2        = (const float*)d_in[10];
    const float* gb        = (const float*)d_in[11];
    const float* bb        = (const float*)d_in[12];
    const float* Wv1       = (const float*)d_in[13];
    const float* bv1       = (const float*)d_in[14];
    const float* gv1       = (const float*)d_in[15];
    const float* btv1      = (const float*)d_in[16];
    const float* Wv2       = (const float*)d_in[17];
    const float* bv2       = (const float*)d_in[18];
    const float* gv2       = (const float*)d_in[19];
    const float* btv2      = (const float*)d_in[20];
    const int* edge_index  = (const int*)d_in[21];
    const int* batch       = (const int*)d_in[22];
    float* outp = (float*)d_out;

    auto au = [](size_t v) { return (v + 255) & ~(size_t)255; };
    char* p = (char*)d_ws;
    u16* h_in   = (u16*)p;  p += au((size_t)N_NODES * DIM * 2);
    u16* z_bf   = (u16*)p;  p += au((size_t)N_NODES * DIM * 2);
    u16* c1_bf  = (u16*)p;  p += au((size_t)N_NODES * HID * 2);
    u16* W1t    = (u16*)p;  p += au((size_t)3 * 32768 * 2);
    u16* W2t    = (u16*)p;  p += au((size_t)3 * 32768 * 2);
    float* pooled = (float*)p;  p += au((size_t)N_GRAPH * DIM * 4);
    float* tpre   = (float*)p;  p += au((size_t)N_GRAPH * HID * 4);
    float* vnpre  = (float*)p;  p += au((size_t)N_GRAPH * DIM * 4);
    float* statsA = (float*)p;  p += au(2048 * 4);
    float* statsB = (float*)p;  p += au(2048 * 4);
    int* rowptr = (int*)p;  p += au((size_t)(N_NODES + 1) * 4);
    int* cursor = (int*)p;  p += au((size_t)N_NODES * 4);
    int2* sE    = (int2*)p;

    const float invN = 1.0f / (float)N_NODES;
    const float invG = 1.0f / (float)N_GRAPH;
    const int total4 = N_NODES * DIM / 4;

    // ---- one-time prep ----
    hipMemsetAsync(cursor, 0, N_NODES * sizeof(int), stream);
    hipMemsetAsync(pooled, 0, (size_t)N_GRAPH * DIM * sizeof(float), stream);
    hist_kernel<<<(N_EDGES + 255) / 256, 256, 0, stream>>>(edge_index, cursor);
    scan_kernel<<<1, 1024, 0, stream>>>(cursor, rowptr);   // also re-zeroes cursor
    scatter_kernel<<<(N_EDGES + 255) / 256, 256, 0, stream>>>(edge_index, rowptr, cursor, sE);
    wconv_kernel<<<768, 256, 0, stream>>>(W1, W2, W1t, W2t);

    for (int l = 0; l < N_LAYER; ++l) {
        float* cur = (l & 1) ? statsB : statsA;
        float* prv = (l & 1) ? statsA : statsB;

        if (l == 0)
            hin_kernel<false, 0><<<(total4 + 255) / 256, 256, 0, stream>>>(
                x, nullptr, nullptr, nullptr, nullptr, 0.f, batch,
                vn_emb, nullptr, nullptr, nullptr, nullptr, nullptr, 0.f,
                h_in, total4);
        else
            hin_kernel<true, 1><<<(total4 + 255) / 256, 256, 0, stream>>>(
                outp, prv + 512, prv + 640, gb + (size_t)(l - 1) * DIM, bb + (size_t)(l - 1) * DIM,
                invN, batch,
                nullptr, vnpre, prv + 1280, prv + 1408,
                gv2 + (size_t)(l - 1) * DIM, btv2 + (size_t)(l - 1) * DIM, invG,
                h_in, total4);

        if (l < N_LAYER - 1)
            pooled_chunk_kernel<<<(N_NODES + PCHUNK - 1) / PCHUNK, 128, 0, stream>>>(
                h_in, batch, pooled);

        aggr_kernel<<<(N_NODES + 3) / 4, 256, 0, stream>>>(
            rowptr, sE, edge_attr, We + (size_t)l * EFEAT * DIM, be + (size_t)l * DIM,
            h_in, z_bf, cur);

        // c1 = z @ W1 + b1 (bf16 out, stats -> sum1/ss1). LDS-free MFMA.
        dim3 g1d((N_NODES + 127) / 128, HID / 128);
        gemm_mfma_kernel<DIM, 4, true><<<g1d, 256, 0, stream>>>(
            z_bf, W1t + (size_t)l * 32768, b1 + (size_t)l * HID,
            (void*)c1_bf, cur + 0, cur + 256, N_NODES, HID);

        // c1 <- relu(bn(c1)) in place
        bnrelu_kernel<<<(N_NODES * HID / 8 + 255) / 256, 256, 0, stream>>>(
            c1_bf, cur + 0, cur + 256, g1v + (size_t)l * HID, bt1 + (size_t)l * HID, invN,
            N_NODES * HID / 8);

        // h = c1 @ W2 + b2 (fp32 out, stats -> sum2/ss2)
        dim3 g2d((N_NODES + 127) / 128, DIM / 64);
        gemm_mfma_kernel<HID, 2, false><<<g2d, 256, 0, stream>>>(
            c1_bf, W2t + (size_t)l * 32768, b2 + (size_t)l * DIM,
            (void*)outp, cur + 512, cur + 640, N_NODES, DIM);

        if (l < N_LAYER - 1) {
            dim3 g3d(N_GRAPH / 64, HID / 64);
            if (l == 0)
                gemm_kernel<2, false><<<g3d, 256, 0, stream>>>(
                    pooled, nullptr, vn_emb,
                    nullptr, nullptr, nullptr, nullptr, 0.f,
                    Wv1 + (size_t)l * DIM * HID, bv1 + (size_t)l * HID,
                    tpre, cur + 768, cur + 1024, N_GRAPH, DIM, HID, nullptr);
            else
                gemm_kernel<3, false><<<g3d, 256, 0, stream>>>(
                    pooled, vnpre, nullptr,
                    prv + 1280, prv + 1408, gv2 + (size_t)(l - 1) * DIM, btv2 + (size_t)(l - 1) * DIM, invG,
                    Wv1 + (size_t)l * DIM * HID, bv1 + (size_t)l * HID,
                    tpre, cur + 768, cur + 1024, N_GRAPH, DIM, HID, nullptr);

            dim3 g4d(N_GRAPH / 64, DIM / 64);
            gemm_kernel<1, true><<<g4d, 256, 0, stream>>>(
                tpre, nullptr, nullptr,
                cur + 768, cur + 1024, gv1 + (size_t)l * HID, btv1 + (size_t)l * HID, invG,
                Wv2 + (size_t)l * HID * DIM, bv2 + (size_t)l * DIM,
                vnpre, cur + 1280, cur + 1408, N_GRAPH, HID, DIM, pooled);
        }
    }

    float* lastStats = statsA;   // layer 2 parity 0
    final_bn_kernel<<<(total4 + 255) / 256, 256, 0, stream>>>(
        outp, lastStats + 512, lastStats + 640, gb + (size_t)2 * DIM, bb + (size_t)2 * DIM, invN, total4);
}